// Round 12
// baseline (135.168 us; speedup 1.0000x reference)
//
#include <hip/hip_runtime.h>
#include <hip/hip_bf16.h>
#include <math.h>

#define DIM   768
#define HID   128
#define H2    256
#define NENT  128
#define SPAN  16
#define NCLS  5

// ---- ws layout (bytes) ----
#define POOLB_OFF 0
#define HEPB_OFF  196608
#define TEPB_OFF  (HEPB_OFF + 8388608)
#define TCLSB_OFF (TEPB_OFF + 8388608)
#define WB_OFF    (TCLSB_OFF + 655360)
#define TOKB_OFF  21168128
#define GATES_OFF (TOKB_OFF + 9437184)
#define PREDT_OFF 21168128

typedef __attribute__((ext_vector_type(8))) short bf16x8;
typedef __attribute__((ext_vector_type(4))) float f32x4;

__device__ __forceinline__ float sigmoidf_(float x) { return 1.0f / (1.0f + __expf(-x)); }

__device__ __forceinline__ unsigned short f2bf(float x) {
    __hip_bfloat16 h = __float2bfloat16(x);
    return *reinterpret_cast<unsigned short*>(&h);
}

// ---------------- prep: wconv + conv_tcls + gather_toks fused ----------------
__global__ __launch_bounds__(256)
void prep_kernel(const float* __restrict__ Whf, const float* __restrict__ Whb,
                 const float* __restrict__ Wtf, const float* __restrict__ Wtb,
                 const float* __restrict__ Wef, const float* __restrict__ Web,
                 const float* __restrict__ Tcls, const float* __restrict__ enc,
                 const int* __restrict__ idx_h, const int* __restrict__ idx_t,
                 const int* __restrict__ idx_e,
                 unsigned short* __restrict__ WB, unsigned short* __restrict__ TB,
                 unsigned short* __restrict__ tokB)
{
    const int bb = blockIdx.x;
    const int tid = threadIdx.x;
    if (bb < 1728) {
        int gid = bb * 256 + tid;                        // < 442368
        int t2  = gid / 73728;
        int rem = gid % 73728;
        int n   = rem / 192;
        int c4  = rem % 192;
        int gate = n >> 7, j = n & 127;
        int srow = (gate == 0) ? j : (gate == 1) ? 256 + j : 384 + j;
        const float* W = (t2 == 0) ? Whf : (t2 == 1) ? Whb : (t2 == 2) ? Wtf :
                         (t2 == 3) ? Wtb : (t2 == 4) ? Wef : Web;
        float4 v = ((const float4*)(W + srow * DIM))[c4];
        unsigned short* d = WB + ((size_t)(t2 * 384 + n)) * DIM + c4 * 4;
        d[0] = f2bf(v.x); d[1] = f2bf(v.y); d[2] = f2bf(v.z); d[3] = f2bf(v.w);
    } else if (bb < 3008) {
        int idx = (bb - 1728) * 256 + tid;               // < 327680
        int b = idx / (NCLS * H2);
        int r = idx % (NCLS * H2);
        int m = r >> 8, c = r & 255;
        TB[((m << 8) + c) * H2 + b] = f2bf(Tcls[idx]);
    } else {
        int gid = (bb - 3008) * 256 + tid;               // < 6144*192
        int r  = gid / 192, c4 = gid % 192;
        int type = r >> 11;
        int rem  = r & 2047;
        const int* idx = (type == 0) ? idx_h : (type == 1) ? idx_t : idx_e;
        int row = idx[rem];
        float4 v = ((const float4*)(enc + (size_t)row * DIM))[c4];
        unsigned short h4[4] = { f2bf(v.x), f2bf(v.y), f2bf(v.z), f2bf(v.w) };
        *(uint2*)(tokB + (size_t)r * DIM + c4 * 4) = *(uint2*)h4;
    }
}

// ---------------- gates GEMM (NT), LDS-staged 2-phase double-buffer ----------------
__global__ __launch_bounds__(256)
void gates_mfma(const unsigned short* __restrict__ tokB,
                const unsigned short* __restrict__ WB,
                float* __restrict__ gates)
{
    __shared__ unsigned short As[2][128 * 64];
    __shared__ unsigned short Bs[2][128 * 64];
    const int lbid = ((int)blockIdx.x & 7) * 36 + ((int)blockIdx.x >> 3);  // bijective
    const int type = lbid / 96;
    const int rem  = lbid % 96;
    const int mb0  = (rem / 6) * 128;
    const int nb0  = (rem % 6) * 128;
    const int tid = threadIdx.x;
    const int w = tid >> 6, l = tid & 63;
    const int lr = l & 15, lg = l >> 4;
    const unsigned short* A = tokB + (size_t)type * 2048 * DIM + (size_t)mb0 * DIM;
    const unsigned short* B = WB   + (size_t)type * 768  * DIM + (size_t)nb0 * DIM;

    const int sr0 = tid >> 3;
    const int sc  = tid & 7;

    bf16x8 ra[4], rb[4];
    #define LOADT(kt)                                                        \
        {                                                                    \
            const int koff = (kt) * 64 + sc * 8;                             \
            _Pragma("unroll")                                                \
            for (int p = 0; p < 4; ++p) {                                    \
                int rr = sr0 + p * 32;                                       \
                ra[p] = *(const bf16x8*)(A + (size_t)rr * DIM + koff);       \
                rb[p] = *(const bf16x8*)(B + (size_t)rr * DIM + koff);       \
            }                                                                \
        }
    #define WRITET(buf)                                                      \
        {                                                                    \
            _Pragma("unroll")                                                \
            for (int p = 0; p < 4; ++p) {                                    \
                int rr = sr0 + p * 32;                                       \
                int bo = (rr * 128 + sc * 16) ^ ((rr & 7) << 4);             \
                *(bf16x8*)((char*)As[buf] + bo) = ra[p];                     \
                *(bf16x8*)((char*)Bs[buf] + bo) = rb[p];                     \
            }                                                                \
        }

    f32x4 acc[4][4];
    #pragma unroll
    for (int mt = 0; mt < 4; ++mt)
        #pragma unroll
        for (int nt = 0; nt < 4; ++nt) acc[mt][nt] = (f32x4){0.f, 0.f, 0.f, 0.f};

    const int am0 = (w & 1) * 64;
    const int bn0 = (w >> 1) * 64;

    LOADT(0);
    WRITET(0);
    __syncthreads();

    int cur = 0;
    #pragma unroll 1
    for (int kt = 0; kt < 12; ++kt) {
        if (kt + 1 < 12) LOADT(kt + 1);

        #pragma unroll
        for (int ks = 0; ks < 2; ++ks) {
            bf16x8 af[4], bf[4];
            #pragma unroll
            for (int mt = 0; mt < 4; ++mt) {
                int rr = am0 + mt * 16 + lr;
                int bo = (rr * 128 + ks * 64 + lg * 16) ^ ((rr & 7) << 4);
                af[mt] = *(const bf16x8*)((const char*)As[cur] + bo);
            }
            #pragma unroll
            for (int nt = 0; nt < 4; ++nt) {
                int rr = bn0 + nt * 16 + lr;
                int bo = (rr * 128 + ks * 64 + lg * 16) ^ ((rr & 7) << 4);
                bf[nt] = *(const bf16x8*)((const char*)Bs[cur] + bo);
            }
            #pragma unroll
            for (int mt = 0; mt < 4; ++mt)
                #pragma unroll
                for (int nt = 0; nt < 4; ++nt)
                    acc[mt][nt] = __builtin_amdgcn_mfma_f32_16x16x32_bf16(af[mt], bf[nt], acc[mt][nt], 0, 0, 0);
        }

        if (kt + 1 < 12) {
            WRITET(cur ^ 1);
        }
        __syncthreads();
        cur ^= 1;
    }
    #undef LOADT
    #undef WRITET

    float* C = gates + (size_t)type * 2048 * 768 + (size_t)mb0 * 768 + nb0;
    #pragma unroll
    for (int mt = 0; mt < 4; ++mt)
        #pragma unroll
        for (int nt = 0; nt < 4; ++nt)
            #pragma unroll
            for (int r = 0; r < 4; ++r)
                C[(size_t)(am0 + mt * 16 + lg * 4 + r) * 768 + bn0 + nt * 16 + lr] = acc[mt][nt][r];
}

// ---------------- pool epilogue ----------------
__global__ __launch_bounds__(256)
void pool_epilogue(const float* __restrict__ gates,
                   const float* __restrict__ bhf, const float* __restrict__ bhb,
                   const float* __restrict__ btf, const float* __restrict__ btb,
                   const float* __restrict__ bef, const float* __restrict__ beb,
                   unsigned short* __restrict__ poolB)
{
    const int type = blockIdx.x >> 7;
    const int ent  = blockIdx.x & 127;
    const int tid  = threadIdx.x;
    const int dir  = tid >> 7;
    const int j    = tid & 127;
    const float* Bv = (type == 0) ? (dir ? bhb : bhf)
                    : (type == 1) ? (dir ? btb : btf)
                                  : (dir ? beb : bef);
    const float bi = Bv[j], bg = Bv[2 * HID + j], bo = Bv[3 * HID + j];
    const float* g0 = gates + ((size_t)type * 2048 + ent * 16) * 768 + dir * 384 + j;
    float hmax = -1e30f;
    #pragma unroll
    for (int l = 0; l < SPAN; ++l) {
        const float* gr = g0 + l * 768;
        float iv = sigmoidf_(gr[0]   + bi);
        float gv = tanhf(   gr[128] + bg);
        float ov = sigmoidf_(gr[256] + bo);
        hmax = fmaxf(hmax, ov * tanhf(iv * gv));
    }
    poolB[(size_t)(type * NENT + ent) * H2 + dir * HID + j] = f2bf(hmax);
}

// ---------------- pair: fused gemm1+gemm2, XCD-swizzled b assignment ----------------
// block = (t, beta): W[a][k] = sum_c T_t[a][beta][c]*Ee[k][c]; out[beta][k][i] = sum_a W[a][k]*Hx[i][a]
// grid 512; 1024 thr = 16 waves. LDS 128 KB.
// XCD swizzle: lbid = (bid&7)*64 + bid>>3 -> XCD x gets CONTIGUOUS b in [64x,64x+64):
// b's low bits (address bits 10-17 of the T read stream) sweep fully within each XCD,
// avoiding channel/L3-bank camping (round 6-11: XCD x saw only b===x mod 8 -> ~1.9 TB/s cap).
__global__ __launch_bounds__(1024)
void pair_mfma(const unsigned short* __restrict__ EeB,
               const unsigned short* __restrict__ HeB,
               const unsigned short* __restrict__ TeB,
               const float* __restrict__ T0, const float* __restrict__ T1,
               unsigned short* __restrict__ hepN,   // [256][128][128]
               unsigned short* __restrict__ tepN)
{
    __shared__ __align__(16) char smem[131072];
    const int bid = blockIdx.x;
    const int lbid = (bid & 7) * 64 + (bid >> 3);   // bijective on [0,512)
    const int t = lbid >> 8;
    const int b = lbid & 255;
    const float* T = t ? T1 : T0;
    const unsigned short* Hx = t ? TeB : HeB;
    unsigned short* outp = t ? tepN : hepN;
    const int tid = threadIdx.x;
    const int w = tid >> 6, l = tid & 63;
    const int lr = l & 15, lg = l >> 4;

    // ---- stage T[:,b,:] fp32 -> slab bf16 swz
    {
        const int r0 = tid >> 5;
        const int ch = tid & 31;
        #pragma unroll
        for (int p = 0; p < 8; ++p) {
            int row = p * 32 + r0;
            const float* src = T + ((size_t)row * 256 + b) * 256 + ch * 8;
            float4 v0 = ((const float4*)src)[0];
            float4 v1 = ((const float4*)src)[1];
            bf16x8 hv; unsigned short* hp = (unsigned short*)&hv;
            hp[0]=f2bf(v0.x); hp[1]=f2bf(v0.y); hp[2]=f2bf(v0.z); hp[3]=f2bf(v0.w);
            hp[4]=f2bf(v1.x); hp[5]=f2bf(v1.y); hp[6]=f2bf(v1.z); hp[7]=f2bf(v1.w);
            int bo = (row * 512 + ch * 16) ^ ((row & 7) << 4);
            *(bf16x8*)(smem + bo) = hv;
        }
    }
    __syncthreads();

    // ---- P1: W[a][k]; 16 waves: aw = w&3 (64a), kw = w>>2 (32k)
    f32x4 acc1[4][2];
    {
        const int aw = (w & 3) * 64;
        const int kw = (w >> 2) * 32;
        #pragma unroll
        for (int mt = 0; mt < 4; ++mt)
            #pragma unroll
            for (int nt = 0; nt < 2; ++nt) acc1[mt][nt] = (f32x4){0.f, 0.f, 0.f, 0.f};

        #pragma unroll
        for (int ks = 0; ks < 8; ++ks) {
            bf16x8 af[4], bf[2];
            #pragma unroll
            for (int mt = 0; mt < 4; ++mt) {
                int ar = aw + mt * 16 + lr;
                int bo = (ar * 512 + (ks * 32 + lg * 8) * 2) ^ ((ar & 7) << 4);
                af[mt] = *(const bf16x8*)(smem + bo);
            }
            #pragma unroll
            for (int nt = 0; nt < 2; ++nt)
                bf[nt] = *(const bf16x8*)(EeB + (kw + nt * 16 + lr) * H2 + ks * 32 + lg * 8);
            #pragma unroll
            for (int mt = 0; mt < 4; ++mt)
                #pragma unroll
                for (int nt = 0; nt < 2; ++nt)
                    acc1[mt][nt] = __builtin_amdgcn_mfma_f32_16x16x32_bf16(af[mt], bf[nt], acc1[mt][nt], 0, 0, 0);
        }
    }
    __syncthreads();   // slab fully consumed

    // ---- write WT[k][a] bf16 swz into smem[0:64K]
    {
        const int aw = (w & 3) * 64;
        const int kw = (w >> 2) * 32;
        #pragma unroll
        for (int mt = 0; mt < 4; ++mt)
            #pragma unroll
            for (int nt = 0; nt < 2; ++nt) {
                int k  = kw + nt * 16 + lr;
                int a0 = aw + mt * 16 + lg * 4;
                unsigned short h4[4] = { f2bf(acc1[mt][nt][0]), f2bf(acc1[mt][nt][1]),
                                         f2bf(acc1[mt][nt][2]), f2bf(acc1[mt][nt][3]) };
                int bo = (k * 512 + a0 * 2) ^ ((k & 7) << 4);
                *(uint2*)(smem + bo) = *(uint2*)h4;
            }
    }
    __syncthreads();

    // ---- P2: out[b][k][i]; 16 waves: kw2 = w>>3 (64k), iw = w&7 (16i)
    {
        const int kw2 = (w >> 3) * 64;
        const int iw  = (w & 7) * 16;
        f32x4 acc2[4];
        #pragma unroll
        for (int mt = 0; mt < 4; ++mt) acc2[mt] = (f32x4){0.f, 0.f, 0.f, 0.f};

        #pragma unroll
        for (int ks = 0; ks < 8; ++ks) {
            bf16x8 af[4], bf;
            #pragma unroll
            for (int mt = 0; mt < 4; ++mt) {
                int kr = kw2 + mt * 16 + lr;
                int bo = (kr * 512 + (ks * 32 + lg * 8) * 2) ^ ((kr & 7) << 4);
                af[mt] = *(const bf16x8*)(smem + bo);
            }
            bf = *(const bf16x8*)(Hx + (iw + lr) * H2 + ks * 32 + lg * 8);
            #pragma unroll
            for (int mt = 0; mt < 4; ++mt)
                acc2[mt] = __builtin_amdgcn_mfma_f32_16x16x32_bf16(af[mt], bf, acc2[mt], 0, 0, 0);
        }
        unsigned short* po = outp + (size_t)b * (128 * 128);
        #pragma unroll
        for (int mt = 0; mt < 4; ++mt)
            #pragma unroll
            for (int r = 0; r < 4; ++r) {
                int k = kw2 + mt * 16 + lg * 4 + r;
                int i = iw + lr;
                po[k * 128 + i] = f2bf(acc2[mt][r]);
            }
    }
}

// ---------------- step3: block per (k, j-half); m-loop inside ----------------
__global__ __launch_bounds__(512)
void step3_mfma(const unsigned short* __restrict__ hepN,  // [256 beta][128 k][128 i]
                const unsigned short* __restrict__ tepN,  // [256 b][128 k][128 j]
                const unsigned short* __restrict__ TclsB, // [m][c][b]
                float* __restrict__ predT)
{
    __shared__ unsigned short hepS[128 * 256];  // [i][beta] swz, 64 KB
    __shared__ unsigned short tepS[64 * 256];   // [j][b] swz, 32 KB
    __shared__ unsigned short WS[64 * 256];     // [j][c] swz, 32 KB
    const int lbid = (blockIdx.x & 7) * 32 + (blockIdx.x >> 3);
    const int k  = lbid >> 1;
    const int jh = lbid & 1;
    const int tid = threadIdx.x;
    const int w  = tid >> 6;
    const int l  = tid & 63;
    const int lr = l & 15;
    const int lg = l >> 4;
    const int swz = (lr & 7) << 4;

    #pragma unroll
    for (int q = 0; q < 4; ++q) {
        int bcol = q * 64 + l;
        bf16x8 v = *(const bf16x8*)(tepN + ((size_t)bcol * 128 + k) * 128 + jh * 64 + w * 8);
        #pragma unroll
        for (int r = 0; r < 8; ++r) {
            int j = w * 8 + r;
            int bo = (j * 512 + bcol * 2) ^ (r << 4);
            *(unsigned short*)((char*)tepS + bo) = ((unsigned short*)&v)[r];
        }
    }
    #pragma unroll
    for (int s = 0; s < 2; ++s)
        #pragma unroll
        for (int q = 0; q < 4; ++q) {
            int bcol = q * 64 + l;
            bf16x8 v = *(const bf16x8*)(hepN + ((size_t)bcol * 128 + k) * 128 + w * 16 + s * 8);
            #pragma unroll
            for (int r = 0; r < 8; ++r) {
                int i = w * 16 + s * 8 + r;
                int bo = (i * 512 + bcol * 2) ^ (r << 4);
                *(unsigned short*)((char*)hepS + bo) = ((unsigned short*)&v)[r];
            }
        }
    __syncthreads();

    bf16x8 ha[8];
    #pragma unroll
    for (int ks = 0; ks < 8; ++ks) {
        int ir = w * 16 + lr;
        int bo = (ir * 512 + (ks * 32 + lg * 8) * 2) ^ ((ir & 7) << 4);
        ha[ks] = *(const bf16x8*)((const char*)hepS + bo);
    }

    #pragma unroll 1
    for (int m = 0; m < NCLS; ++m) {
        {
            const unsigned short* tcm = TclsB + (size_t)m * (H2 * H2);
            f32x4 acc1[4][2];
            #pragma unroll
            for (int jt = 0; jt < 4; ++jt)
                #pragma unroll
                for (int ct = 0; ct < 2; ++ct) acc1[jt][ct] = (f32x4){0.f, 0.f, 0.f, 0.f};

            #pragma unroll
            for (int ks = 0; ks < 8; ++ks) {
                bf16x8 a[4], bb[2];
                #pragma unroll
                for (int jt = 0; jt < 4; ++jt) {
                    int byteoff = ((((jt * 16 + lr) << 8) + ks * 32 + lg * 8) << 1) ^ swz;
                    a[jt] = *(const bf16x8*)((const char*)tepS + byteoff);
                }
                #pragma unroll
                for (int ct = 0; ct < 2; ++ct)
                    bb[ct] = *(const bf16x8*)(tcm + (size_t)(w * 32 + ct * 16 + lr) * H2 + ks * 32 + lg * 8);
                #pragma unroll
                for (int jt = 0; jt < 4; ++jt)
                    #pragma unroll
                    for (int ct = 0; ct < 2; ++ct)
                        acc1[jt][ct] = __builtin_amdgcn_mfma_f32_16x16x32_bf16(a[jt], bb[ct], acc1[jt][ct], 0, 0, 0);
            }
            #pragma unroll
            for (int jt = 0; jt < 4; ++jt)
                #pragma unroll
                for (int ct = 0; ct < 2; ++ct)
                    #pragma unroll
                    for (int r = 0; r < 4; ++r) {
                        int j = jt * 16 + lg * 4 + r;
                        int c = w * 32 + ct * 16 + lr;
                        int byteoff = ((((j << 8) + c)) << 1) ^ ((j & 7) << 4);
                        *(unsigned short*)((char*)WS + byteoff) = f2bf(acc1[jt][ct][r]);
                    }
        }
        __syncthreads();

        {
            f32x4 acc2[4];
            #pragma unroll
            for (int jt = 0; jt < 4; ++jt) acc2[jt] = (f32x4){0.f, 0.f, 0.f, 0.f};

            #pragma unroll
            for (int ks = 0; ks < 8; ++ks) {
                #pragma unroll
                for (int jt = 0; jt < 4; ++jt) {
                    int byteoff = ((((jt * 16 + lr) << 8) + ks * 32 + lg * 8) << 1) ^ swz;
                    bf16x8 wb = *(const bf16x8*)((const char*)WS + byteoff);
                    acc2[jt] = __builtin_amdgcn_mfma_f32_16x16x32_bf16(ha[ks], wb, acc2[jt], 0, 0, 0);
                }
            }
            float* po = predT + (size_t)(k * NCLS + m) * (NENT * NENT);
            #pragma unroll
            for (int jt = 0; jt < 4; ++jt)
                #pragma unroll
                for (int r = 0; r < 4; ++r) {
                    int i = w * 16 + lg * 4 + r;
                    int j = jh * 64 + jt * 16 + lr;
                    po[i * NENT + j] = acc2[jt][r];
                }
        }
        __syncthreads();
    }
}

// ---------------- transpose: predT[km][ij] -> out[ij][km] ----------------
__global__ __launch_bounds__(256)
void transpose_out(const float* __restrict__ predT, float* __restrict__ out)
{
    __shared__ float Ls[160][33];
    const int bid = blockIdx.x;
    const int ij0 = (bid >> 2) * 32;
    const int km0 = (bid & 3) * 160;
    const int t = threadIdx.x;

    #pragma unroll
    for (int q = 0; q < 20; ++q) {
        int r = (t >> 5) + q * 8;
        int c = t & 31;
        Ls[r][c] = predT[(size_t)(km0 + r) * 16384 + ij0 + c];
    }
    __syncthreads();
    for (int idx = t; idx < 32 * 160; idx += 256) {
        int r = idx / 160, c = idx % 160;
        out[(size_t)(ij0 + r) * 640 + km0 + c] = Ls[c][r];
    }
}

extern "C" void kernel_launch(void* const* d_in, const int* in_sizes, int n_in,
                              void* d_out, int out_size, void* d_ws, size_t ws_size,
                              hipStream_t stream)
{
    (void)in_sizes; (void)n_in; (void)out_size; (void)ws_size;
    const float* enc  = (const float*)d_in[0];
    const int*   hidx = (const int*)d_in[1];
    const int*   tidx = (const int*)d_in[2];
    const int*   eidx = (const int*)d_in[3];
    const float* Whf = (const float*)d_in[4];
    const float* bhf = (const float*)d_in[5];
    const float* Whb = (const float*)d_in[6];
    const float* bhb = (const float*)d_in[7];
    const float* Wtf = (const float*)d_in[8];
    const float* btf = (const float*)d_in[9];
    const float* Wtb = (const float*)d_in[10];
    const float* btb = (const float*)d_in[11];
    const float* Wef = (const float*)d_in[12];
    const float* bef = (const float*)d_in[13];
    const float* Web = (const float*)d_in[14];
    const float* beb = (const float*)d_in[15];
    const float* T_he  = (const float*)d_in[16];
    const float* T_te  = (const float*)d_in[17];
    const float* T_cls = (const float*)d_in[18];

    float* out = (float*)d_out;
    char*  ws  = (char*)d_ws;
    unsigned short* poolB = (unsigned short*)(ws + POOLB_OFF);
    unsigned short* hepN  = (unsigned short*)(ws + HEPB_OFF);
    unsigned short* tepN  = (unsigned short*)(ws + TEPB_OFF);
    unsigned short* TclsB = (unsigned short*)(ws + TCLSB_OFF);
    unsigned short* WB    = (unsigned short*)(ws + WB_OFF);
    unsigned short* tokB  = (unsigned short*)(ws + TOKB_OFF);
    float*          gates = (float*)(ws + GATES_OFF);
    float*          predT = (float*)(ws + PREDT_OFF);

    unsigned short* HeB = poolB;
    unsigned short* TeB = poolB + 1 * NENT * H2;
    unsigned short* EeB = poolB + 2 * NENT * H2;

    prep_kernel<<<7616, 256, 0, stream>>>(Whf, Whb, Wtf, Wtb, Wef, Web,
                                          T_cls, enc, hidx, tidx, eidx,
                                          WB, TclsB, tokB);

    gates_mfma<<<288, 256, 0, stream>>>(tokB, WB, gates);

    pool_epilogue<<<384, 256, 0, stream>>>(gates, bhf, bhb, btf, btb, bef, beb, poolB);

    pair_mfma<<<512, 1024, 0, stream>>>(EeB, HeB, TeB, T_he, T_te, hepN, tepN);

    step3_mfma<<<256, 512, 0, stream>>>(hepN, tepN, TclsB, predT);

    transpose_out<<<2048, 256, 0, stream>>>(predT, out);
}